// Round 5
// baseline (206.164 us; speedup 1.0000x reference)
//
#include <hip/hip_runtime.h>
#include <math.h>

// YOLO loss — R5: forced-MLP register streaming (cell-pair dwordx4).
// Theory: R0-R4 all ~2.8 TB/s logical because real per-wave MLP never
// materialized — compiler clamped register kernels to 20-32 VGPR and issued
// loads in wait-clusters (R1/R3), and DMA variants serialized per-tile.
// Here each lane owns TWO consecutive cells: 15+10+2 float4 + 1 int2 = 28
// independent dwordx4-class loads (440 B/lane) issued back-to-back and
// pinned above all consumers by sched_barrier(0). ~130+ VGPR, ~12 waves/CU
// -> ~300 KB/CU in flight vs ~3 KB before. All fragment indexing is
// compile-time constant (no scratch); bi-select via ternaries.

#define BLOCK 256

// CELL: PB = pf base (0 or 30), TB = tf base (0 or 20)
#define CELL(PB, TB, tbv, mf) do {                                            \
    if (mf) {                                                                 \
        float txc = tbv.x / 14.0f, tyc = tbv.y / 14.0f;                       \
        float t0_ = txc - 0.5f * tbv.z, t1_ = tyc - 0.5f * tbv.w;             \
        float t2_ = txc + 0.5f * tbv.z, t3_ = tyc + 0.5f * tbv.w;             \
        float area_t = (t2_ - t0_) * (t3_ - t1_);                             \
        float iou[2];                                                         \
        _Pragma("unroll")                                                     \
        for (int b_ = 0; b_ < 2; ++b_) {                                      \
            float px = pf[PB + 5*b_ + 0] / 14.0f;                             \
            float py = pf[PB + 5*b_ + 1] / 14.0f;                             \
            float w_ = pf[PB + 5*b_ + 2], h_ = pf[PB + 5*b_ + 3];             \
            float q0_ = px - 0.5f * w_, q1_ = py - 0.5f * h_;                 \
            float q2_ = px + 0.5f * w_, q3_ = py + 0.5f * h_;                 \
            float lt0 = fmaxf(t0_, q0_), lt1 = fmaxf(t1_, q1_);               \
            float rb0 = fminf(t2_, q2_), rb1 = fminf(t3_, q3_);               \
            float ww = fmaxf(rb0 - lt0, 0.f), hh = fmaxf(rb1 - lt1, 0.f);     \
            float inter = ww * hh;                                            \
            float area_p = (q2_ - q0_) * (q3_ - q1_);                         \
            iou[b_] = inter / (area_t + area_p - inter);                      \
        }                                                                     \
        int bi_ = (iou[1] > iou[0]) ? 1 : 0;   /* first-max tie rule */       \
        float bx_ = bi_ ? pf[PB+5] : pf[PB+0];                                \
        float by_ = bi_ ? pf[PB+6] : pf[PB+1];                                \
        float bw_ = bi_ ? pf[PB+7] : pf[PB+2];                                \
        float bh_ = bi_ ? pf[PB+8] : pf[PB+3];                                \
        float bc_ = bi_ ? pf[PB+9] : pf[PB+4];                                \
        float biou = bi_ ? iou[1] : iou[0];                                   \
        float dx_ = bx_ - tbv.x, dy_ = by_ - tbv.y;                           \
        float swd = sqrtf(bw_) - sqrtf(tbv.z);                                \
        float shd = sqrtf(bh_) - sqrtf(tbv.w);                                \
        reg = fmaf(5.0f, dx_*dx_ + dy_*dy_ + swd*swd + shd*shd, reg);         \
        float dco = biou - bc_;                                               \
        cont = fmaf(dco, dco, cont);                                          \
        _Pragma("unroll")                                                     \
        for (int k_ = 0; k_ < 20; ++k_) {                                     \
            float d_ = tf[TB + k_] - pf[PB + 10 + k_];                        \
            cls = fmaf(d_, d_, cls);                                          \
        }                                                                     \
    } else {                                                                  \
        noobj += 0.5f * (pf[PB+4]*pf[PB+4] + pf[PB+9]*pf[PB+9]);              \
    }                                                                         \
} while (0)

__global__ __launch_bounds__(BLOCK, 2) void k_yolo(
    const float* __restrict__ pred,
    const float* __restrict__ tbox,
    const float* __restrict__ tcls,
    const int*   __restrict__ mask,
    float4*      __restrict__ partial,
    int n_cells)
{
    const int tid = threadIdx.x;
    const long long p = (long long)blockIdx.x * BLOCK + tid;   // cell-pair id

    float cls = 0.f, noobj = 0.f, reg = 0.f, cont = 0.f;

    if (2 * p + 1 < (long long)n_cells) {
        const float4* pq = reinterpret_cast<const float4*>(pred) + p * 15;
        const float4* tq = reinterpret_cast<const float4*>(tcls) + p * 10;
        const float4* bq = reinterpret_cast<const float4*>(tbox) + p * 2;

        // ---- 28 independent vector loads, oldest = first consumed ----
        int2   mm = reinterpret_cast<const int2*>(mask)[p];
        float4 b0 = bq[0], b1 = bq[1];
        float4 q0  = pq[0],  q1  = pq[1],  q2  = pq[2],  q3  = pq[3];
        float4 q4  = pq[4],  q5  = pq[5],  q6  = pq[6],  q7  = pq[7];
        float4 q8  = pq[8],  q9  = pq[9],  q10 = pq[10], q11 = pq[11];
        float4 q12 = pq[12], q13 = pq[13], q14 = pq[14];
        float4 t0 = tq[0], t1 = tq[1], t2 = tq[2], t3 = tq[3], t4 = tq[4];
        float4 t5 = tq[5], t6 = tq[6], t7 = tq[7], t8 = tq[8], t9 = tq[9];
        // pin the whole cluster above every consumer: forces back-to-back
        // issue + full register allocation (the MLP R1/R3 never got)
        __builtin_amdgcn_sched_barrier(0);

        // register renames (SROA; all indices compile-time constant)
        const float pf[60] = {
            q0.x,q0.y,q0.z,q0.w,   q1.x,q1.y,q1.z,q1.w,   q2.x,q2.y,q2.z,q2.w,
            q3.x,q3.y,q3.z,q3.w,   q4.x,q4.y,q4.z,q4.w,   q5.x,q5.y,q5.z,q5.w,
            q6.x,q6.y,q6.z,q6.w,   q7.x,q7.y,q7.z,q7.w,   q8.x,q8.y,q8.z,q8.w,
            q9.x,q9.y,q9.z,q9.w,   q10.x,q10.y,q10.z,q10.w, q11.x,q11.y,q11.z,q11.w,
            q12.x,q12.y,q12.z,q12.w, q13.x,q13.y,q13.z,q13.w, q14.x,q14.y,q14.z,q14.w };
        const float tf[40] = {
            t0.x,t0.y,t0.z,t0.w, t1.x,t1.y,t1.z,t1.w, t2.x,t2.y,t2.z,t2.w,
            t3.x,t3.y,t3.z,t3.w, t4.x,t4.y,t4.z,t4.w, t5.x,t5.y,t5.z,t5.w,
            t6.x,t6.y,t6.z,t6.w, t7.x,t7.y,t7.z,t7.w, t8.x,t8.y,t8.z,t8.w,
            t9.x,t9.y,t9.z,t9.w };

        CELL(0,  0,  b0, mm.x);
        CELL(30, 20, b1, mm.y);
    } else if (2 * p < (long long)n_cells) {
        // lone last cell (odd n_cells only; dead for bench shape)
        const long long c = 2 * p;
        const float* f = pred + c * 30;
        const int mf = mask[c];
        const float4 tbv = reinterpret_cast<const float4*>(tbox)[c];
        if (mf) {
            float txc = tbv.x / 14.0f, tyc = tbv.y / 14.0f;
            float t0_ = txc - 0.5f * tbv.z, t1_ = tyc - 0.5f * tbv.w;
            float t2_ = txc + 0.5f * tbv.z, t3_ = tyc + 0.5f * tbv.w;
            float area_t = (t2_ - t0_) * (t3_ - t1_);
            float iou[2];
            #pragma unroll
            for (int b_ = 0; b_ < 2; ++b_) {
                float px = f[5*b_+0] / 14.0f, py = f[5*b_+1] / 14.0f;
                float w_ = f[5*b_+2], h_ = f[5*b_+3];
                float q0_ = px - 0.5f * w_, q1_ = py - 0.5f * h_;
                float q2_ = px + 0.5f * w_, q3_ = py + 0.5f * h_;
                float lt0 = fmaxf(t0_, q0_), lt1 = fmaxf(t1_, q1_);
                float rb0 = fminf(t2_, q2_), rb1 = fminf(t3_, q3_);
                float ww = fmaxf(rb0 - lt0, 0.f), hh = fmaxf(rb1 - lt1, 0.f);
                float inter = ww * hh;
                float area_p = (q2_ - q0_) * (q3_ - q1_);
                iou[b_] = inter / (area_t + area_p - inter);
            }
            int bi_ = (iou[1] > iou[0]) ? 1 : 0;
            float bx_ = f[5*bi_+0], by_ = f[5*bi_+1];
            float bw_ = f[5*bi_+2], bh_ = f[5*bi_+3], bc_ = f[5*bi_+4];
            float biou = bi_ ? iou[1] : iou[0];
            float dx_ = bx_ - tbv.x, dy_ = by_ - tbv.y;
            float swd = sqrtf(bw_) - sqrtf(tbv.z);
            float shd = sqrtf(bh_) - sqrtf(tbv.w);
            reg = fmaf(5.0f, dx_*dx_ + dy_*dy_ + swd*swd + shd*shd, reg);
            float dco = biou - bc_;
            cont = fmaf(dco, dco, cont);
            const float* g = tcls + c * 20;
            #pragma unroll
            for (int k_ = 0; k_ < 20; ++k_) {
                float d_ = g[k_] - f[10 + k_];
                cls = fmaf(d_, d_, cls);
            }
        } else {
            noobj += 0.5f * (f[4]*f[4] + f[9]*f[9]);
        }
    }

    // ---- wave shuffle reduce, then block reduce, store partial ----
    #pragma unroll
    for (int off = 32; off; off >>= 1) {
        cls   += __shfl_down(cls,   off, 64);
        noobj += __shfl_down(noobj, off, 64);
        reg   += __shfl_down(reg,   off, 64);
        cont  += __shfl_down(cont,  off, 64);
    }
    __shared__ float4 swr[4];
    const int lane = tid & 63, w = tid >> 6;
    if (lane == 0) swr[w] = make_float4(cls, noobj, reg, cont);
    __syncthreads();
    if (tid == 0) {
        float4 a = swr[0];
        #pragma unroll
        for (int i = 1; i < 4; ++i) {
            float4 b = swr[i];
            a.x += b.x; a.y += b.y; a.z += b.z; a.w += b.w;
        }
        partial[blockIdx.x] = a;
    }
}

__global__ __launch_bounds__(256) void k_final(
    const float4* __restrict__ partial, int nblocks,
    float* __restrict__ out, float invN)
{
    float4 acc = make_float4(0.f, 0.f, 0.f, 0.f);
    for (int b = threadIdx.x; b < nblocks; b += 256) {
        float4 v = partial[b];
        acc.x += v.x; acc.y += v.y; acc.z += v.z; acc.w += v.w;
    }
    #pragma unroll
    for (int off = 32; off; off >>= 1) {
        acc.x += __shfl_down(acc.x, off, 64);
        acc.y += __shfl_down(acc.y, off, 64);
        acc.z += __shfl_down(acc.z, off, 64);
        acc.w += __shfl_down(acc.w, off, 64);
    }
    __shared__ float4 sw[4];
    int lane = threadIdx.x & 63, w = threadIdx.x >> 6;
    if (lane == 0) sw[w] = acc;
    __syncthreads();
    if (threadIdx.x == 0) {
        float cls = 0.f, noobj = 0.f, reg = 0.f, cont = 0.f;
        #pragma unroll
        for (int i = 0; i < 4; ++i) {
            cls += sw[i].x; noobj += sw[i].y; reg += sw[i].z; cont += sw[i].w;
        }
        out[0] = (cls + noobj + reg + cont) * invN;
        out[1] = reg;
        out[2] = cont;
        out[3] = noobj;
        out[4] = cls;
    }
}

extern "C" void kernel_launch(void* const* d_in, const int* in_sizes, int n_in,
                              void* d_out, int out_size, void* d_ws, size_t ws_size,
                              hipStream_t stream) {
    const float* pred = (const float*)d_in[0];   // (N,14,14,30) f32
    const float* tbox = (const float*)d_in[1];   // (N,14,14,4)  f32
    const float* tcls = (const float*)d_in[2];   // (N,14,14,20) f32
    const int*   mask = (const int*)d_in[3];     // (N,14,14)    int32
    float* out = (float*)d_out;
    float4* partial = (float4*)d_ws;

    int n_cells = in_sizes[3];
    int N = in_sizes[0] / (14 * 14 * 30);
    long long nslots = ((long long)n_cells + 1) / 2;          // cell-pairs (ceil)
    int nblocks = (int)((nslots + BLOCK - 1) / BLOCK);

    hipLaunchKernelGGL(k_yolo, dim3(nblocks), dim3(BLOCK), 0, stream,
                       pred, tbox, tcls, mask, partial, n_cells);
    hipLaunchKernelGGL(k_final, dim3(1), dim3(256), 0, stream,
                       partial, nblocks, out, 1.0f / (float)N);
}

// Round 6
// 202.074 us; speedup vs baseline: 1.0202x; 1.0202x over previous
//
#include <hip/hip_runtime.h>
#include <math.h>

// YOLO loss — R6: demand-minimal loads on the R3 streaming structure.
// Theory: six structures pinned at 63-71 us; replay dispatches with ~0 HBM
// traffic (fully L3-resident) take the SAME time as 87-MB-from-HBM ones ->
// the wall is CU ingress of REQUESTED bytes (~4.5 B/cy/CU), not HBM. So
// request fewer bytes: unmasked cells (~50%) need only the 10 box/conf
// floats of pred — skip their 20 class floats, their tcls (80 B) and tbox
// (16 B). mask issues first; box float2s unconditional (fill the pipe
// during the mask round-trip); class/tcls/tbox conditional on mflag.
// Logical traffic 177 -> ~106-130 MB.

#define BLOCK 256

__global__ __launch_bounds__(BLOCK, 6) void k_yolo(
    const float*  __restrict__ pred,
    const float4* __restrict__ tbox4,
    const float4* __restrict__ tcls4,
    const int*    __restrict__ mask,
    float4*       __restrict__ partial,
    int n_cells)
{
    const int tid  = threadIdx.x;
    const int cell = blockIdx.x * BLOCK + tid;
    const bool valid = cell < n_cells;

    float cls = 0.f, noobj = 0.f, reg = 0.f, cont = 0.f;

    if (valid) {
        const float2* pc2 = reinterpret_cast<const float2*>(pred + (size_t)cell * 30);

        // ---- earliest: mask (gates everything bulky) + box floats ----
        const int mflag = mask[cell];
        float2 v0 = pc2[0], v1 = pc2[1], v2 = pc2[2], v3 = pc2[3], v4 = pc2[4];
        // floats 0..9: box0 = (v0.x,v0.y,v1.x,v1.y, conf v2.x)
        //              box1 = (v2.y,v3.x,v3.y,v4.x, conf v4.y)

        if (mflag) {
            // ---- masked-only loads: tbox, class half of pred, tcls ----
            const float4 tb = tbox4[cell];
            float2 v5  = pc2[5],  v6  = pc2[6],  v7  = pc2[7],  v8  = pc2[8],  v9 = pc2[9];
            float2 v10 = pc2[10], v11 = pc2[11], v12 = pc2[12], v13 = pc2[13], v14 = pc2[14];
            const float4* t4 = tcls4 + (size_t)cell * 5;
            float4 tc0 = t4[0], tc1 = t4[1], tc2 = t4[2], tc3 = t4[3], tc4 = t4[4];

            float txc = tb.x / 14.0f, tyc = tb.y / 14.0f;
            float t0 = txc - 0.5f * tb.z, t1 = tyc - 0.5f * tb.w;
            float t2c = txc + 0.5f * tb.z, t3 = tyc + 0.5f * tb.w;
            float area_t = (t2c - t0) * (t3 - t1);
            float bx[2] = { v0.x, v2.y }, by[2] = { v0.y, v3.x };
            float bw[2] = { v1.x, v3.y }, bh[2] = { v1.y, v4.x };
            float bcf[2] = { v2.x, v4.y };
            float iou[2];
            #pragma unroll
            for (int b = 0; b < 2; ++b) {
                float px = bx[b] / 14.0f, py = by[b] / 14.0f;
                float q0 = px - 0.5f * bw[b], q1 = py - 0.5f * bh[b];
                float q2 = px + 0.5f * bw[b], q3 = py + 0.5f * bh[b];
                float lt0 = fmaxf(t0, q0), lt1 = fmaxf(t1, q1);
                float rb0 = fminf(t2c, q2), rb1 = fminf(t3, q3);
                float ww = fmaxf(rb0 - lt0, 0.f), hh = fmaxf(rb1 - lt1, 0.f);
                float inter = ww * hh;
                float area_p = (q2 - q0) * (q3 - q1);
                iou[b] = inter / (area_t + area_p - inter);
            }
            int bi = (iou[1] > iou[0]) ? 1 : 0;   // first-max tie rule
            float dx = bx[bi] - tb.x, dy = by[bi] - tb.y;
            float swd = sqrtf(bw[bi]) - sqrtf(tb.z);
            float shd = sqrtf(bh[bi]) - sqrtf(tb.w);
            reg = 5.0f * (dx*dx + dy*dy + swd*swd + shd*shd);
            float dco = iou[bi] - bcf[bi];
            cont = dco * dco;

            // class floats k0..k19 = v5..v14 ; tcls = tc0..tc4
            float d;
            d = tc0.x - v5.x;  cls = fmaf(d, d, cls);
            d = tc0.y - v5.y;  cls = fmaf(d, d, cls);
            d = tc0.z - v6.x;  cls = fmaf(d, d, cls);
            d = tc0.w - v6.y;  cls = fmaf(d, d, cls);
            d = tc1.x - v7.x;  cls = fmaf(d, d, cls);
            d = tc1.y - v7.y;  cls = fmaf(d, d, cls);
            d = tc1.z - v8.x;  cls = fmaf(d, d, cls);
            d = tc1.w - v8.y;  cls = fmaf(d, d, cls);
            d = tc2.x - v9.x;  cls = fmaf(d, d, cls);
            d = tc2.y - v9.y;  cls = fmaf(d, d, cls);
            d = tc2.z - v10.x; cls = fmaf(d, d, cls);
            d = tc2.w - v10.y; cls = fmaf(d, d, cls);
            d = tc3.x - v11.x; cls = fmaf(d, d, cls);
            d = tc3.y - v11.y; cls = fmaf(d, d, cls);
            d = tc3.z - v12.x; cls = fmaf(d, d, cls);
            d = tc3.w - v12.y; cls = fmaf(d, d, cls);
            d = tc4.x - v13.x; cls = fmaf(d, d, cls);
            d = tc4.y - v13.y; cls = fmaf(d, d, cls);
            d = tc4.z - v14.x; cls = fmaf(d, d, cls);
            d = tc4.w - v14.y; cls = fmaf(d, d, cls);
        } else {
            noobj = 0.5f * (v2.x * v2.x + v4.y * v4.y);
        }
    }

    // ---- wave shuffle reduce, then block reduce, store partial ----
    #pragma unroll
    for (int off = 32; off; off >>= 1) {
        cls   += __shfl_down(cls,   off, 64);
        noobj += __shfl_down(noobj, off, 64);
        reg   += __shfl_down(reg,   off, 64);
        cont  += __shfl_down(cont,  off, 64);
    }
    __shared__ float4 swr[4];
    const int lane = tid & 63, w = tid >> 6;
    if (lane == 0) swr[w] = make_float4(cls, noobj, reg, cont);
    __syncthreads();
    if (tid == 0) {
        float4 a = swr[0];
        #pragma unroll
        for (int i = 1; i < 4; ++i) {
            float4 b = swr[i];
            a.x += b.x; a.y += b.y; a.z += b.z; a.w += b.w;
        }
        partial[blockIdx.x] = a;
    }
}

__global__ __launch_bounds__(256) void k_final(
    const float4* __restrict__ partial, int nblocks,
    float* __restrict__ out, float invN)
{
    float4 acc = make_float4(0.f, 0.f, 0.f, 0.f);
    for (int b = threadIdx.x; b < nblocks; b += 256) {
        float4 v = partial[b];
        acc.x += v.x; acc.y += v.y; acc.z += v.z; acc.w += v.w;
    }
    #pragma unroll
    for (int off = 32; off; off >>= 1) {
        acc.x += __shfl_down(acc.x, off, 64);
        acc.y += __shfl_down(acc.y, off, 64);
        acc.z += __shfl_down(acc.z, off, 64);
        acc.w += __shfl_down(acc.w, off, 64);
    }
    __shared__ float4 sw[4];
    int lane = threadIdx.x & 63, w = threadIdx.x >> 6;
    if (lane == 0) sw[w] = acc;
    __syncthreads();
    if (threadIdx.x == 0) {
        float cls = 0.f, noobj = 0.f, reg = 0.f, cont = 0.f;
        #pragma unroll
        for (int i = 0; i < 4; ++i) {
            cls += sw[i].x; noobj += sw[i].y; reg += sw[i].z; cont += sw[i].w;
        }
        out[0] = (cls + noobj + reg + cont) * invN;
        out[1] = reg;
        out[2] = cont;
        out[3] = noobj;
        out[4] = cls;
    }
}

extern "C" void kernel_launch(void* const* d_in, const int* in_sizes, int n_in,
                              void* d_out, int out_size, void* d_ws, size_t ws_size,
                              hipStream_t stream) {
    const float*  pred  = (const float*)d_in[0];   // (N,14,14,30) f32
    const float4* tbox4 = (const float4*)d_in[1];  // (N,14,14,4)  f32
    const float4* tcls4 = (const float4*)d_in[2];  // (N,14,14,20) f32
    const int*    mask  = (const int*)d_in[3];     // (N,14,14)    int32
    float* out = (float*)d_out;
    float4* partial = (float4*)d_ws;

    int n_cells = in_sizes[3];
    int N = in_sizes[0] / (14 * 14 * 30);
    int nblocks = (n_cells + BLOCK - 1) / BLOCK;

    hipLaunchKernelGGL(k_yolo, dim3(nblocks), dim3(BLOCK), 0, stream,
                       pred, tbox4, tcls4, mask, partial, n_cells);
    hipLaunchKernelGGL(k_final, dim3(1), dim3(256), 0, stream,
                       partial, nblocks, out, 1.0f / (float)N);
}